// Round 1
// baseline (90.095 us; speedup 1.0000x reference)
//
#include <hip/hip_runtime.h>

#define HSZ 4096
#define BSZ 4096
#define PSZ 512

// ws layout:
// [0, 16384)      colsum  float[4096]
// [16384, 16392)  normsum double
// [16416, 32800)  best    float[4096]

__global__ __launch_bounds__(256) void k_reduce(const float* __restrict__ x,
                                                float* __restrict__ colsum,
                                                double* __restrict__ normsum,
                                                int rows_per_block) {
    const int tid = threadIdx.x;
    const int r0 = blockIdx.x * rows_per_block;
    float4 c0 = {0,0,0,0}, c1 = {0,0,0,0}, c2 = {0,0,0,0}, c3 = {0,0,0,0};
    __shared__ float wavepart[4];
    double normacc = 0.0;  // only thread 0 accumulates

    for (int r = 0; r < rows_per_block; ++r) {
        const float4* row = (const float4*)(x + (size_t)(r0 + r) * HSZ);
        float4 a = row[tid];
        float4 b = row[256 + tid];
        float4 c = row[512 + tid];
        float4 d = row[768 + tid];
        c0.x += a.x; c0.y += a.y; c0.z += a.z; c0.w += a.w;
        c1.x += b.x; c1.y += b.y; c1.z += b.z; c1.w += b.w;
        c2.x += c.x; c2.y += c.y; c2.z += c.z; c2.w += c.w;
        c3.x += d.x; c3.y += d.y; c3.z += d.z; c3.w += d.w;
        float sq = a.x*a.x + a.y*a.y + a.z*a.z + a.w*a.w
                 + b.x*b.x + b.y*b.y + b.z*b.z + b.w*b.w
                 + c.x*c.x + c.y*c.y + c.z*c.z + c.w*c.w
                 + d.x*d.x + d.y*d.y + d.z*d.z + d.w*d.w;
        // wave-64 butterfly reduce
        #pragma unroll
        for (int m = 1; m <= 32; m <<= 1) sq += __shfl_xor(sq, m);
        if ((tid & 63) == 0) wavepart[tid >> 6] = sq;
        __syncthreads();
        if (tid == 0) {
            float tot = wavepart[0] + wavepart[1] + wavepart[2] + wavepart[3];
            normacc += sqrt((double)tot);
        }
        __syncthreads();
    }
    if (tid == 0) atomicAdd(normsum, normacc);

    // thread t owns columns {4t..4t+3, 1024+4t.., 2048+4t.., 3072+4t..} — block-disjoint
    const int cb = 4 * tid;
    atomicAdd(&colsum[cb + 0],        c0.x); atomicAdd(&colsum[cb + 1],        c0.y);
    atomicAdd(&colsum[cb + 2],        c0.z); atomicAdd(&colsum[cb + 3],        c0.w);
    atomicAdd(&colsum[1024 + cb + 0], c1.x); atomicAdd(&colsum[1024 + cb + 1], c1.y);
    atomicAdd(&colsum[1024 + cb + 2], c1.z); atomicAdd(&colsum[1024 + cb + 3], c1.w);
    atomicAdd(&colsum[2048 + cb + 0], c2.x); atomicAdd(&colsum[2048 + cb + 1], c2.y);
    atomicAdd(&colsum[2048 + cb + 2], c2.z); atomicAdd(&colsum[2048 + cb + 3], c2.w);
    atomicAdd(&colsum[3072 + cb + 0], c3.x); atomicAdd(&colsum[3072 + cb + 1], c3.y);
    atomicAdd(&colsum[3072 + cb + 2], c3.z); atomicAdd(&colsum[3072 + cb + 3], c3.w);
}

__global__ __launch_bounds__(512) void k_update(
        const float* __restrict__ inertia, const float* __restrict__ cog,
        const float* __restrict__ soc,
        const float* __restrict__ pos, const float* __restrict__ vel,
        const float* __restrict__ pbp, const float* __restrict__ pbf,
        const float* __restrict__ gbp, const float* __restrict__ gbf,
        const float* __restrict__ r1, const float* __restrict__ r2,
        const float* __restrict__ colsum, const double* __restrict__ normsum,
        float* __restrict__ best) {
    const int tid = threadIdx.x;
    __shared__ float vals[PSZ];
    __shared__ int idxs[PSZ];

    const float fitness = (float)(-(*normsum) / (double)BSZ);

    float v = pbf[tid];
    vals[tid] = (fitness > v) ? fitness : v;
    idxs[tid] = tid;
    __syncthreads();
    // argmax, first-occurrence tie-break (lower index wins on equal value)
    for (int s = PSZ / 2; s > 0; s >>= 1) {
        if (tid < s) {
            float vo = vals[tid + s]; int io = idxs[tid + s];
            float vm = vals[tid];     int im = idxs[tid];
            if (vo > vm || (vo == vm && io < im)) { vals[tid] = vo; idxs[tid] = io; }
        }
        __syncthreads();
    }
    const int istar = idxs[0];

    const bool  imp  = fitness > pbf[istar];
    const bool  gimp = fitness > gbf[0];
    const float w    = inertia[0], cw = cog[0], sw = soc[0];
    const float r1v  = r1[istar], r2v = r2[istar];
    const float* posr = pos + (size_t)istar * HSZ;
    const float* velr = vel + (size_t)istar * HSZ;
    const float* pbpr = pbp + (size_t)istar * HSZ;

    for (int h = tid; h < HSZ; h += 512) {
        float xm = colsum[h] * (1.0f / (float)BSZ);
        float p  = posr[h];
        float pb = imp  ? xm : pbpr[h];
        float gb = gimp ? xm : gbp[h];
        float vn = w * velr[h] + cw * r1v * (pb - p) + sw * r2v * (gb - p);
        best[h] = p + vn;
    }
}

__global__ __launch_bounds__(256) void k_add(const float* __restrict__ x,
                                             const float* __restrict__ best,
                                             float* __restrict__ out) {
    const size_t n4 = (size_t)BSZ * HSZ / 4;
    const float4* x4 = (const float4*)x;
    const float4* b4 = (const float4*)best;
    float4* o4 = (float4*)out;
    const size_t stride = (size_t)gridDim.x * blockDim.x;
    for (size_t k = (size_t)blockIdx.x * blockDim.x + threadIdx.x; k < n4; k += stride) {
        float4 xv = x4[k];
        float4 bv = b4[k & (HSZ / 4 - 1)];  // column float4 index = k % 1024
        float4 ov;
        ov.x = xv.x + bv.x; ov.y = xv.y + bv.y;
        ov.z = xv.z + bv.z; ov.w = xv.w + bv.w;
        o4[k] = ov;
    }
}

extern "C" void kernel_launch(void* const* d_in, const int* in_sizes, int n_in,
                              void* d_out, int out_size, void* d_ws, size_t ws_size,
                              hipStream_t stream) {
    const float* x       = (const float*)d_in[0];
    const float* inertia = (const float*)d_in[1];
    const float* cog     = (const float*)d_in[2];
    const float* soc     = (const float*)d_in[3];
    const float* pos     = (const float*)d_in[4];
    const float* vel     = (const float*)d_in[5];
    const float* pbp     = (const float*)d_in[6];
    const float* pbf     = (const float*)d_in[7];
    const float* gbp     = (const float*)d_in[8];
    const float* gbf     = (const float*)d_in[9];
    const float* r1      = (const float*)d_in[10];
    const float* r2      = (const float*)d_in[11];
    float* out = (float*)d_out;

    char* ws = (char*)d_ws;
    float*  colsum  = (float*)ws;
    double* normsum = (double*)(ws + 16384);
    float*  best    = (float*)(ws + 16416);

    // accumulators must be zeroed every call (ws is poisoned, not re-poisoned)
    hipMemsetAsync(ws, 0, 16392, stream);

    k_reduce<<<256, 256, 0, stream>>>(x, colsum, normsum, BSZ / 256);
    k_update<<<1, PSZ, 0, stream>>>(inertia, cog, soc, pos, vel, pbp, pbf, gbp,
                                    gbf, r1, r2, colsum, normsum, best);
    k_add<<<2048, 256, 0, stream>>>(x, best, out);
}

// Round 2
// 56.745 us; speedup vs baseline: 1.5877x; 1.5877x over previous
//
#include <hip/hip_runtime.h>

#define HSZ 4096
#define BSZ 4096
#define PSZ 512

// ---------------- fast path (needs ~16.1 MB ws) ----------------
// ws layout:
// [0, 16777216)                colpartial float[1024][4096]
// [16777216, 16781312)         blocknorm  float[1024]
// [16781312, 16797696)         colsum     float[4096]   (memset 0 each call)
// [16797696, 16814080)         best       float[4096]
#define WS_NEEDED 16814080ull
#define NB1 1024          // k1 blocks, 4 rows each

__global__ __launch_bounds__(256) void k1_reduce(const float* __restrict__ x,
                                                 float* __restrict__ colpartial,
                                                 float* __restrict__ blocknorm) {
    const int tid = threadIdx.x;
    const int b = blockIdx.x;
    const int r0 = b * 4;
    float4 c0 = {0,0,0,0}, c1 = {0,0,0,0}, c2 = {0,0,0,0}, c3 = {0,0,0,0};
    __shared__ float sq[4][256];
    __shared__ float norm4[4];

    #pragma unroll
    for (int r = 0; r < 4; ++r) {
        const float4* row = (const float4*)(x + (size_t)(r0 + r) * HSZ);
        float4 a = row[tid];
        float4 e = row[256 + tid];
        float4 c = row[512 + tid];
        float4 d = row[768 + tid];
        c0.x += a.x; c0.y += a.y; c0.z += a.z; c0.w += a.w;
        c1.x += e.x; c1.y += e.y; c1.z += e.z; c1.w += e.w;
        c2.x += c.x; c2.y += c.y; c2.z += c.z; c2.w += c.w;
        c3.x += d.x; c3.y += d.y; c3.z += d.z; c3.w += d.w;
        sq[r][tid] = a.x*a.x + a.y*a.y + a.z*a.z + a.w*a.w
                   + e.x*e.x + e.y*e.y + e.z*e.z + e.w*e.w
                   + c.x*c.x + c.y*c.y + c.z*c.z + c.w*c.w
                   + d.x*d.x + d.y*d.y + d.z*d.z + d.w*d.w;
    }
    __syncthreads();
    // wave w reduces row w (4 waves, 4 rows)
    {
        const int w = tid >> 6;
        const int l = tid & 63;
        float s = sq[w][l] + sq[w][64 + l] + sq[w][128 + l] + sq[w][192 + l];
        #pragma unroll
        for (int m = 1; m <= 32; m <<= 1) s += __shfl_xor(s, m);
        if (l == 0) norm4[w] = sqrtf(s);
    }
    __syncthreads();
    if (tid == 0)
        blocknorm[b] = norm4[0] + norm4[1] + norm4[2] + norm4[3];

    // coalesced partial-column-sum store (thread t owns cols 4t..4t+3 (+1024k))
    float4* cp = (float4*)(colpartial + (size_t)b * HSZ);
    cp[tid]       = c0;
    cp[256 + tid] = c1;
    cp[512 + tid] = c2;
    cp[768 + tid] = c3;
}

__global__ __launch_bounds__(256) void k2_colsum(const float* __restrict__ colpartial,
                                                 float* __restrict__ colsum) {
    const int id  = blockIdx.x * 256 + threadIdx.x;   // 65536 threads
    const int h   = id & (HSZ - 1);
    const int seg = id >> 12;                         // 0..15, 64 slabs each
    const float* base = colpartial + (size_t)seg * 64 * HSZ + h;
    float s = 0.f;
    #pragma unroll 8
    for (int b = 0; b < 64; ++b) s += base[(size_t)b * HSZ];
    atomicAdd(&colsum[h], s);                         // 16-way contention only
}

__global__ __launch_bounds__(512) void k3_update(
        const float* __restrict__ inertia, const float* __restrict__ cog,
        const float* __restrict__ soc,
        const float* __restrict__ pos, const float* __restrict__ vel,
        const float* __restrict__ pbp, const float* __restrict__ pbf,
        const float* __restrict__ gbp, const float* __restrict__ gbf,
        const float* __restrict__ r1, const float* __restrict__ r2,
        const float* __restrict__ colsum, const float* __restrict__ blocknorm,
        float* __restrict__ best) {
    const int tid = threadIdx.x;
    __shared__ float vals[PSZ];
    __shared__ int idxs[PSZ];
    __shared__ double wsum[8];
    __shared__ float fit_s;

    // fitness = -(sum of 1024 blocknorms)/BSZ, accumulated in double
    double d = (double)blocknorm[tid] + (double)blocknorm[512 + tid];
    #pragma unroll
    for (int m = 1; m <= 32; m <<= 1) d += __shfl_xor(d, m);
    if ((tid & 63) == 0) wsum[tid >> 6] = d;
    __syncthreads();
    if (tid == 0) {
        double tot = 0.0;
        #pragma unroll
        for (int i = 0; i < 8; ++i) tot += wsum[i];
        fit_s = (float)(-tot / (double)BSZ);
    }
    __syncthreads();
    const float fitness = fit_s;

    float v = pbf[tid];
    vals[tid] = (fitness > v) ? fitness : v;
    idxs[tid] = tid;
    __syncthreads();
    for (int s = PSZ / 2; s > 0; s >>= 1) {
        if (tid < s) {
            float vo = vals[tid + s]; int io = idxs[tid + s];
            float vm = vals[tid];     int im = idxs[tid];
            if (vo > vm || (vo == vm && io < im)) { vals[tid] = vo; idxs[tid] = io; }
        }
        __syncthreads();
    }
    const int istar = idxs[0];

    const bool  imp  = fitness > pbf[istar];
    const bool  gimp = fitness > gbf[0];
    const float w    = inertia[0], cw = cog[0], sw = soc[0];
    const float r1v  = r1[istar], r2v = r2[istar];
    const float* posr = pos + (size_t)istar * HSZ;
    const float* velr = vel + (size_t)istar * HSZ;
    const float* pbpr = pbp + (size_t)istar * HSZ;

    for (int h = tid; h < HSZ; h += 512) {
        float xm = colsum[h] * (1.0f / (float)BSZ);
        float p  = posr[h];
        float pb = imp  ? xm : pbpr[h];
        float gb = gimp ? xm : gbp[h];
        float vn = w * velr[h] + cw * r1v * (pb - p) + sw * r2v * (gb - p);
        best[h] = p + vn;
    }
}

__global__ __launch_bounds__(256) void k_add(const float* __restrict__ x,
                                             const float* __restrict__ best,
                                             float* __restrict__ out) {
    const size_t n4 = (size_t)BSZ * HSZ / 4;
    const float4* x4 = (const float4*)x;
    const float4* b4 = (const float4*)best;
    float4* o4 = (float4*)out;
    const size_t stride = (size_t)gridDim.x * blockDim.x;
    for (size_t k = (size_t)blockIdx.x * blockDim.x + threadIdx.x; k < n4; k += stride) {
        float4 xv = x4[k];
        float4 bv = b4[k & (HSZ / 4 - 1)];
        float4 ov;
        ov.x = xv.x + bv.x; ov.y = xv.y + bv.y;
        ov.z = xv.z + bv.z; ov.w = xv.w + bv.w;
        o4[k] = ov;
    }
}

// ---------------- fallback path (old, needs only 32.8 KB ws) ----------------
__global__ __launch_bounds__(256) void f_reduce(const float* __restrict__ x,
                                                float* __restrict__ colsum,
                                                double* __restrict__ normsum,
                                                int rows_per_block) {
    const int tid = threadIdx.x;
    const int r0 = blockIdx.x * rows_per_block;
    float4 c0 = {0,0,0,0}, c1 = {0,0,0,0}, c2 = {0,0,0,0}, c3 = {0,0,0,0};
    __shared__ float wavepart[4];
    double normacc = 0.0;
    for (int r = 0; r < rows_per_block; ++r) {
        const float4* row = (const float4*)(x + (size_t)(r0 + r) * HSZ);
        float4 a = row[tid], b = row[256 + tid], c = row[512 + tid], d = row[768 + tid];
        c0.x += a.x; c0.y += a.y; c0.z += a.z; c0.w += a.w;
        c1.x += b.x; c1.y += b.y; c1.z += b.z; c1.w += b.w;
        c2.x += c.x; c2.y += c.y; c2.z += c.z; c2.w += c.w;
        c3.x += d.x; c3.y += d.y; c3.z += d.z; c3.w += d.w;
        float sq = a.x*a.x + a.y*a.y + a.z*a.z + a.w*a.w
                 + b.x*b.x + b.y*b.y + b.z*b.z + b.w*b.w
                 + c.x*c.x + c.y*c.y + c.z*c.z + c.w*c.w
                 + d.x*d.x + d.y*d.y + d.z*d.z + d.w*d.w;
        #pragma unroll
        for (int m = 1; m <= 32; m <<= 1) sq += __shfl_xor(sq, m);
        if ((tid & 63) == 0) wavepart[tid >> 6] = sq;
        __syncthreads();
        if (tid == 0) {
            float tot = wavepart[0] + wavepart[1] + wavepart[2] + wavepart[3];
            normacc += sqrt((double)tot);
        }
        __syncthreads();
    }
    if (tid == 0) atomicAdd(normsum, normacc);
    const int cb = 4 * tid;
    atomicAdd(&colsum[cb + 0], c0.x); atomicAdd(&colsum[cb + 1], c0.y);
    atomicAdd(&colsum[cb + 2], c0.z); atomicAdd(&colsum[cb + 3], c0.w);
    atomicAdd(&colsum[1024 + cb + 0], c1.x); atomicAdd(&colsum[1024 + cb + 1], c1.y);
    atomicAdd(&colsum[1024 + cb + 2], c1.z); atomicAdd(&colsum[1024 + cb + 3], c1.w);
    atomicAdd(&colsum[2048 + cb + 0], c2.x); atomicAdd(&colsum[2048 + cb + 1], c2.y);
    atomicAdd(&colsum[2048 + cb + 2], c2.z); atomicAdd(&colsum[2048 + cb + 3], c2.w);
    atomicAdd(&colsum[3072 + cb + 0], c3.x); atomicAdd(&colsum[3072 + cb + 1], c3.y);
    atomicAdd(&colsum[3072 + cb + 2], c3.z); atomicAdd(&colsum[3072 + cb + 3], c3.w);
}

__global__ __launch_bounds__(512) void f_update(
        const float* __restrict__ inertia, const float* __restrict__ cog,
        const float* __restrict__ soc,
        const float* __restrict__ pos, const float* __restrict__ vel,
        const float* __restrict__ pbp, const float* __restrict__ pbf,
        const float* __restrict__ gbp, const float* __restrict__ gbf,
        const float* __restrict__ r1, const float* __restrict__ r2,
        const float* __restrict__ colsum, const double* __restrict__ normsum,
        float* __restrict__ best) {
    const int tid = threadIdx.x;
    __shared__ float vals[PSZ];
    __shared__ int idxs[PSZ];
    const float fitness = (float)(-(*normsum) / (double)BSZ);
    float v = pbf[tid];
    vals[tid] = (fitness > v) ? fitness : v;
    idxs[tid] = tid;
    __syncthreads();
    for (int s = PSZ / 2; s > 0; s >>= 1) {
        if (tid < s) {
            float vo = vals[tid + s]; int io = idxs[tid + s];
            float vm = vals[tid];     int im = idxs[tid];
            if (vo > vm || (vo == vm && io < im)) { vals[tid] = vo; idxs[tid] = io; }
        }
        __syncthreads();
    }
    const int istar = idxs[0];
    const bool  imp  = fitness > pbf[istar];
    const bool  gimp = fitness > gbf[0];
    const float w    = inertia[0], cw = cog[0], sw = soc[0];
    const float r1v  = r1[istar], r2v = r2[istar];
    const float* posr = pos + (size_t)istar * HSZ;
    const float* velr = vel + (size_t)istar * HSZ;
    const float* pbpr = pbp + (size_t)istar * HSZ;
    for (int h = tid; h < HSZ; h += 512) {
        float xm = colsum[h] * (1.0f / (float)BSZ);
        float p  = posr[h];
        float pb = imp  ? xm : pbpr[h];
        float gb = gimp ? xm : gbp[h];
        float vn = w * velr[h] + cw * r1v * (pb - p) + sw * r2v * (gb - p);
        best[h] = p + vn;
    }
}

extern "C" void kernel_launch(void* const* d_in, const int* in_sizes, int n_in,
                              void* d_out, int out_size, void* d_ws, size_t ws_size,
                              hipStream_t stream) {
    const float* x       = (const float*)d_in[0];
    const float* inertia = (const float*)d_in[1];
    const float* cog     = (const float*)d_in[2];
    const float* soc     = (const float*)d_in[3];
    const float* pos     = (const float*)d_in[4];
    const float* vel     = (const float*)d_in[5];
    const float* pbp     = (const float*)d_in[6];
    const float* pbf     = (const float*)d_in[7];
    const float* gbp     = (const float*)d_in[8];
    const float* gbf     = (const float*)d_in[9];
    const float* r1      = (const float*)d_in[10];
    const float* r2      = (const float*)d_in[11];
    float* out = (float*)d_out;
    char* ws = (char*)d_ws;

    if (ws_size >= WS_NEEDED) {
        float* colpartial = (float*)ws;
        float* blocknorm  = (float*)(ws + 16777216);
        float* colsum     = (float*)(ws + 16781312);
        float* best       = (float*)(ws + 16797696);

        hipMemsetAsync(colsum, 0, HSZ * sizeof(float), stream);
        k1_reduce<<<NB1, 256, 0, stream>>>(x, colpartial, blocknorm);
        k2_colsum<<<256, 256, 0, stream>>>(colpartial, colsum);
        k3_update<<<1, PSZ, 0, stream>>>(inertia, cog, soc, pos, vel, pbp, pbf,
                                         gbp, gbf, r1, r2, colsum, blocknorm, best);
        k_add<<<4096, 256, 0, stream>>>(x, best, out);
    } else {
        float*  colsum  = (float*)ws;
        double* normsum = (double*)(ws + 16384);
        float*  best    = (float*)(ws + 16416);
        hipMemsetAsync(ws, 0, 16392, stream);
        f_reduce<<<256, 256, 0, stream>>>(x, colsum, normsum, BSZ / 256);
        f_update<<<1, PSZ, 0, stream>>>(inertia, cog, soc, pos, vel, pbp, pbf,
                                        gbp, gbf, r1, r2, colsum, normsum, best);
        k_add<<<2048, 256, 0, stream>>>(x, best, out);
    }
}